// Round 1
// baseline (1041.950 us; speedup 1.0000x reference)
//
#include <hip/hip_runtime.h>
#include <math.h>

#define N 8192
#define M 8192
#define C 96
#define OUT 20
#define LG 2048

#define NSPA 16   // n-splits for argmin pass
#define NSPB 8    // m-splits for uw pass
#define TILE 128

constexpr size_t F4 = 4;
constexpr size_t OFF_DIFF  = 0;                                  // 16 f
constexpr size_t OFF_AL    = 64;                                 // M*3 f
constexpr size_t OFF_RNSSF = OFF_AL    + (size_t)M*3*F4;         // M f
constexpr size_t OFF_UPDF  = OFF_RNSSF + (size_t)M*F4;           // M f
constexpr size_t OFF_RNMF  = OFF_UPDF  + (size_t)M*F4;           // N f
constexpr size_t OFF_NMF2  = OFF_RNMF  + (size_t)N*F4;           // N f
constexpr size_t OFF_VALS  = OFF_NMF2  + (size_t)N*F4;           // LG f
constexpr size_t OFF_MAXV  = OFF_VALS  + (size_t)LG*F4;          // N f
constexpr size_t OFF_PAV   = OFF_MAXV  + (size_t)N*F4;           // M*NSPA f
constexpr size_t OFF_PB    = OFF_PAV   + (size_t)M*NSPA*F4;      // N*NSPB*21 f
constexpr size_t OFF_GTC   = OFF_PB    + (size_t)N*NSPB*21*F4;   // M int
constexpr size_t OFF_SMI   = OFF_GTC   + (size_t)M*F4;           // M int
constexpr size_t OFF_POS   = OFF_SMI   + (size_t)M*F4;           // N int
constexpr size_t OFF_AMAX  = OFF_POS   + (size_t)N*F4;           // N int
constexpr size_t OFF_PAI   = OFF_AMAX  + (size_t)N*F4;           // M*NSPA int
constexpr size_t OFF_FLAGS = OFF_PAI   + (size_t)M*NSPA*F4;      // 2 int

// ---------------------------------------------------------------- 4x4 inverse
__global__ void k_diff(const float* __restrict__ posses, float* __restrict__ diff) {
    if (threadIdx.x != 0 || blockIdx.x != 0) return;
    float a[4][8];
    for (int i = 0; i < 4; i++)
        for (int j = 0; j < 4; j++) {
            a[i][j]     = posses[16 + i*4 + j];   // posses[1]
            a[i][4 + j] = (i == j) ? 1.f : 0.f;
        }
    for (int col = 0; col < 4; col++) {
        int piv = col; float mx = fabsf(a[col][col]);
        for (int r = col + 1; r < 4; r++) {
            float v = fabsf(a[r][col]);
            if (v > mx) { mx = v; piv = r; }
        }
        if (piv != col)
            for (int j = 0; j < 8; j++) { float t = a[col][j]; a[col][j] = a[piv][j]; a[piv][j] = t; }
        float inv = 1.0f / a[col][col];
        for (int j = 0; j < 8; j++) a[col][j] *= inv;
        for (int r = 0; r < 4; r++) {
            if (r == col) continue;
            float f = a[r][col];
            for (int j = 0; j < 8; j++) a[r][j] -= f * a[col][j];
        }
    }
    // diff = inv(posses[1]) @ posses[0]
    for (int i = 0; i < 4; i++)
        for (int j = 0; j < 4; j++) {
            float s = 0.f;
            for (int k = 0; k < 4; k++) s += a[i][4 + k] * posses[k*4 + j];
            diff[i*4 + j] = s;
        }
}

// ---------------------------------------------------------------- per-m prep
__global__ void k_prep_m(const float* __restrict__ ssf, const float* __restrict__ scoords,
                         const float* __restrict__ gt, const int* __restrict__ ran_mask,
                         const float* __restrict__ diff,
                         float* __restrict__ al, float* __restrict__ rnssf,
                         float* __restrict__ updf, int* __restrict__ gtcls) {
    int m = blockIdx.x * 256 + threadIdx.x;
    if (m >= M) return;
    float x = scoords[m*3], y = scoords[m*3+1], z = scoords[m*3+2];
    #pragma unroll
    for (int j = 0; j < 3; j++)
        al[m*3 + j] = diff[j*4+0]*x + diff[j*4+1]*y + diff[j*4+2]*z + diff[j*4+3];
    float s = 0.f;
    const float4* r4 = (const float4*)(ssf + (size_t)m * C);
    #pragma unroll
    for (int c = 0; c < 24; c++) {
        float4 v = r4[c];
        s += v.x*v.x + v.y*v.y + v.z*v.z + v.w*v.w;
    }
    rnssf[m] = 1.0f / sqrtf(s);
    int best = 0; float bv = gt[(size_t)m*OUT];
    #pragma unroll
    for (int k = 1; k < OUT; k++) {
        float v = gt[(size_t)m*OUT + k];
        if (v > bv) { bv = v; best = k; }
    }
    gtcls[m] = best;
    updf[m] = (best < 9 || m < LG || ran_mask[m] == 1) ? 1.f : 0.f;
}

// ---------------------------------------------------------------- per-n prep
__global__ void k_prep_n(const float* __restrict__ mf, float* __restrict__ rnmf,
                         float* __restrict__ nmf2) {
    int n = blockIdx.x * 256 + threadIdx.x;
    if (n >= N) return;
    float s = 0.f;
    const float4* r4 = (const float4*)(mf + (size_t)n * C);
    #pragma unroll
    for (int c = 0; c < 24; c++) {
        float4 v = r4[c];
        s += v.x*v.x + v.y*v.y + v.z*v.z + v.w*v.w;
    }
    nmf2[n] = s;
    rnmf[n] = 1.0f / sqrtf(s);
}

// ---------------------------------------------------------------- pass A: argmin over n per m
__global__ __launch_bounds__(256) void k_argmin(
        const float* __restrict__ mf, const float* __restrict__ ori,
        const float* __restrict__ rnmf, const float* __restrict__ ssf,
        const float* __restrict__ al, const float* __restrict__ rnssf,
        float* __restrict__ pav, int* __restrict__ pai) {
    __shared__ float4 s_mf[TILE * 24];
    __shared__ float  s_ori[TILE * 3];
    __shared__ float  s_rn[TILE];
    int t = threadIdx.x;
    int m = blockIdx.x * 256 + t;
    int sp = blockIdx.y;

    float4 rs[24];
    const float4* srow = (const float4*)(ssf + (size_t)m * C);
    #pragma unroll
    for (int c = 0; c < 24; c++) rs[c] = srow[c];
    float rm = rnssf[m];
    float ax = al[m*3], ay = al[m*3+1], az = al[m*3+2];

    float best = 3.4e38f; int bidx = 0;
    int n_begin = sp * (N / NSPA);
    for (int n0 = n_begin; n0 < n_begin + N / NSPA; n0 += TILE) {
        const float4* g = (const float4*)(mf + (size_t)n0 * C);
        for (int i = t; i < TILE * 24; i += 256) s_mf[i] = g[i];
        for (int i = t; i < TILE * 3;  i += 256) s_ori[i] = ori[n0*3 + i];
        for (int i = t; i < TILE;      i += 256) s_rn[i] = rnmf[n0 + i];
        __syncthreads();
        for (int j = 0; j < TILE; j++) {
            float4 acc = {0.f, 0.f, 0.f, 0.f};
            #pragma unroll
            for (int c = 0; c < 24; c++) {
                float4 v = s_mf[j*24 + c];
                acc.x = fmaf(v.x, rs[c].x, acc.x);
                acc.y = fmaf(v.y, rs[c].y, acc.y);
                acc.z = fmaf(v.z, rs[c].z, acc.z);
                acc.w = fmaf(v.w, rs[c].w, acc.w);
            }
            float dot = (acc.x + acc.y) + (acc.z + acc.w);
            float dx = s_ori[j*3] - ax, dy = s_ori[j*3+1] - ay, dz = s_ori[j*3+2] - az;
            float d2 = dx*dx + dy*dy + dz*dz;
            float sim = 2.0f - dot * (s_rn[j] * rm) - expf(-2.0f * d2);
            if (sim < best) { best = sim; bidx = n0 + j; }
        }
        __syncthreads();
    }
    pav[(size_t)sp * M + m] = best;
    pai[(size_t)sp * M + m] = bidx;
}

__global__ void k_argmin_reduce(const float* __restrict__ pav, const int* __restrict__ pai,
                                int* __restrict__ smi, float* __restrict__ out_smi) {
    int m = blockIdx.x * 256 + threadIdx.x;
    if (m >= M) return;
    float best = 3.4e38f; int bidx = 0;
    for (int sp = 0; sp < NSPA; sp++) {
        float v = pav[(size_t)sp * M + m];
        if (v < best) { best = v; bidx = pai[(size_t)sp * M + m]; }  // strict <: earlier n wins
    }
    smi[m] = bidx;
    out_smi[m] = (float)bidx;
}

// ---------------------------------------------------------------- pass B: class-binned weight sums
__global__ __launch_bounds__(256) void k_uw_part(
        const float* __restrict__ mf, const float* __restrict__ ori,
        const float* __restrict__ nmf2, const int* __restrict__ smi,
        const int* __restrict__ gtcls, const float* __restrict__ updf,
        float* __restrict__ pb) {
    __shared__ float4 s_f[TILE * 24];
    __shared__ float  s_c[TILE * 3];
    __shared__ float  s_n2[TILE];
    __shared__ float  s_u[TILE];
    __shared__ int    s_cl[TILE];
    __shared__ float  bins[256 * 21];   // stride 21: 2-way bank alias (free)
    int t = threadIdx.x;
    int n = blockIdx.x * 256 + t;
    int sp = blockIdx.y;

    float4 rn[24];
    const float4* nrow = (const float4*)(mf + (size_t)n * C);
    #pragma unroll
    for (int c = 0; c < 24; c++) rn[c] = nrow[c];
    float n2n = nmf2[n];
    float ox = ori[n*3], oy = ori[n*3+1], oz = ori[n*3+2];

    #pragma unroll
    for (int k = 0; k < OUT; k++) bins[t*21 + k] = 0.f;
    float tot = 0.f;

    int m_begin = sp * (M / NSPB);
    for (int m0 = m_begin; m0 < m_begin + M / NSPB; m0 += TILE) {
        {   // stage gathered mid rows: 2 threads per row
            int r = t >> 1, h = t & 1;
            int s = smi[m0 + r];
            const float4* src = (const float4*)(mf + (size_t)s * C);
            #pragma unroll
            for (int q = 0; q < 12; q++) s_f[r*24 + h*12 + q] = src[h*12 + q];
            if (h == 0) {
                s_c[r*3]   = ori[s*3];
                s_c[r*3+1] = ori[s*3+1];
                s_c[r*3+2] = ori[s*3+2];
                s_n2[r] = nmf2[s];
                s_cl[r] = gtcls[m0 + r];
                s_u[r]  = updf[m0 + r];
            }
        }
        __syncthreads();
        for (int j = 0; j < TILE; j++) {
            float4 acc = {0.f, 0.f, 0.f, 0.f};
            #pragma unroll
            for (int c = 0; c < 24; c++) {
                float4 v = s_f[j*24 + c];
                acc.x = fmaf(v.x, rn[c].x, acc.x);
                acc.y = fmaf(v.y, rn[c].y, acc.y);
                acc.z = fmaf(v.z, rn[c].z, acc.z);
                acc.w = fmaf(v.w, rn[c].w, acc.w);
            }
            float dot = (acc.x + acc.y) + (acc.z + acc.w);
            float fd = fmaxf(n2n + s_n2[j] - 2.0f * dot, 0.0f);
            float dx = ox - s_c[j*3], dy = oy - s_c[j*3+1], dz = oz - s_c[j*3+2];
            float dc = dx*dx + dy*dy + dz*dz;
            float w = expf(-8.0f * dc - (0.5f/0.09f) * fd) * s_u[j];
            tot += w;
            bins[t*21 + s_cl[j]] += w;
        }
        __syncthreads();
    }
    size_t base = ((size_t)sp * N + n) * 21;
    #pragma unroll
    for (int k = 0; k < OUT; k++) pb[base + k] = bins[t*21 + k];
    pb[base + OUT] = tot;
}

__global__ void k_uw_final(const float* __restrict__ pb, const float* __restrict__ svp,
                           float* __restrict__ out_uw, float* __restrict__ out_spu) {
    int n = blockIdx.x * 256 + threadIdx.x;
    if (n >= N) return;
    float s[OUT]; float tot = 0.f;
    #pragma unroll
    for (int k = 0; k < OUT; k++) s[k] = 0.f;
    for (int sp = 0; sp < NSPB; sp++) {
        size_t base = ((size_t)sp * N + n) * 21;
        #pragma unroll
        for (int k = 0; k < OUT; k++) s[k] += pb[base + k];
        tot += pb[base + OUT];
    }
    float rden = 1.0f / (tot + 1e-16f);
    float p[OUT]; float mx = -3.4e38f;
    #pragma unroll
    for (int k = 0; k < OUT; k++) { p[k] = svp[(size_t)n*OUT + k]; mx = fmaxf(mx, p[k]); }
    float es = 0.f;
    #pragma unroll
    for (int k = 0; k < OUT; k++) { p[k] = expf(p[k] - mx); es += p[k]; }
    float res = 1.0f / es;
    #pragma unroll
    for (int k = 0; k < OUT; k++) {
        float uw = s[k] * rden;
        out_uw[(size_t)n*OUT + k] = uw;
        out_spu[(size_t)n*OUT + k] = 0.5f * (p[k] * res) + 0.5f * uw;
    }
}

// ---------------------------------------------------------------- scatter (lg rows, last-wins)
__global__ void k_scatter_pre(const int* __restrict__ smi, const int* __restrict__ gtcls,
                              const float* __restrict__ spu, float* __restrict__ vals,
                              int* __restrict__ pos, int* __restrict__ flags) {
    int i = blockIdx.x * 256 + threadIdx.x;
    if (i >= LG) return;
    int idx = smi[i];
    float v = spu[(size_t)idx*OUT + gtcls[i]];
    vals[i] = v;
    if (v > 0.1f) atomicOr(&flags[0], 1);
    atomicMax(&pos[idx], i);
}

__global__ void k_scatter_apply(const int* __restrict__ smi, const int* __restrict__ gtcls,
                                const float* __restrict__ vals, const int* __restrict__ pos,
                                const int* __restrict__ flags, float* __restrict__ spu) {
    int i = blockIdx.x * 256 + threadIdx.x;
    if (i >= LG) return;
    int idx = smi[i];
    if (pos[idx] != i) return;               // last occurrence wins (np semantics)
    float v = vals[i];
    bool tmp = flags[0] ? (v > 0.1f) : (v > 0.0f);
    if (!tmp) return;                        // else-branch writes row unchanged: no-op
    int cls = gtcls[i];
    #pragma unroll
    for (int k = 0; k < OUT; k++) spu[(size_t)idx*OUT + k] = (k == cls) ? 1.0f : 0.0f;
}

// ---------------------------------------------------------------- trust / finalize
__global__ void k_trust_pre(const float* __restrict__ spu, float* __restrict__ maxv,
                            int* __restrict__ amax, int* __restrict__ flags) {
    int n = blockIdx.x * 256 + threadIdx.x;
    if (n >= N) return;
    float best = spu[(size_t)n*OUT]; int bi = 0;
    #pragma unroll
    for (int k = 1; k < OUT; k++) {
        float v = spu[(size_t)n*OUT + k];
        if (v > best) { best = v; bi = k; }   // strict >: first occurrence
    }
    maxv[n] = best; amax[n] = bi;
    if (best >= 0.9f) atomicOr(&flags[1], 1);
}

__global__ void k_finalize(const float* __restrict__ mf, const float* __restrict__ ori,
                           const float* __restrict__ maxv, const int* __restrict__ amax,
                           const int* __restrict__ flags,
                           float* __restrict__ out_trust, float* __restrict__ out_mf,
                           float* __restrict__ out_ori, float* __restrict__ out_pre) {
    int n = blockIdx.x * 256 + threadIdx.x;
    if (n >= N) return;
    float mv = maxv[n];
    bool tr = flags[1] ? (mv >= 0.9f) : (mv >= 0.85f);
    float m = tr ? 1.f : 0.f;
    out_trust[n] = m;
    const float4* src = (const float4*)(mf + (size_t)n * C);
    float4* dst = (float4*)(out_mf + (size_t)n * C);
    #pragma unroll
    for (int c = 0; c < 24; c++) {
        float4 v = src[c];
        v.x *= m; v.y *= m; v.z *= m; v.w *= m;
        dst[c] = v;
    }
    out_ori[n*3]   = ori[n*3]   * m;
    out_ori[n*3+1] = ori[n*3+1] * m;
    out_ori[n*3+2] = ori[n*3+2] * m;
    int bi = amax[n];
    #pragma unroll
    for (int k = 0; k < OUT; k++) out_pre[(size_t)n*OUT + k] = (k == bi) ? m : 0.f;
}

// ---------------------------------------------------------------- launch
extern "C" void kernel_launch(void* const* d_in, const int* in_sizes, int n_in,
                              void* d_out, int out_size, void* d_ws, size_t ws_size,
                              hipStream_t stream) {
    (void)in_sizes; (void)n_in; (void)out_size; (void)ws_size;
    const float* ssf     = (const float*)d_in[0];
    const float* scoords = (const float*)d_in[1];
    const float* gt      = (const float*)d_in[2];
    const float* svp     = (const float*)d_in[3];
    const float* mf      = (const float*)d_in[4];
    const float* ori     = (const float*)d_in[5];
    const float* posses  = (const float*)d_in[6];
    const int*   ran     = (const int*)d_in[7];

    float* out = (float*)d_out;
    float* out_trust = out;
    float* out_mf    = out_trust + N;
    float* out_ori   = out_mf + (size_t)N*C;
    float* out_pre   = out_ori + (size_t)N*3;
    float* out_uw    = out_pre + (size_t)N*OUT;
    float* out_spu   = out_uw  + (size_t)N*OUT;
    float* out_smi   = out_spu + (size_t)N*OUT;

    char* ws = (char*)d_ws;
    float* w_diff  = (float*)(ws + OFF_DIFF);
    float* w_al    = (float*)(ws + OFF_AL);
    float* w_rnssf = (float*)(ws + OFF_RNSSF);
    float* w_updf  = (float*)(ws + OFF_UPDF);
    float* w_rnmf  = (float*)(ws + OFF_RNMF);
    float* w_nmf2  = (float*)(ws + OFF_NMF2);
    float* w_vals  = (float*)(ws + OFF_VALS);
    float* w_maxv  = (float*)(ws + OFF_MAXV);
    float* w_pav   = (float*)(ws + OFF_PAV);
    float* w_pb    = (float*)(ws + OFF_PB);
    int*   w_gtc   = (int*)(ws + OFF_GTC);
    int*   w_smi   = (int*)(ws + OFF_SMI);
    int*   w_pos   = (int*)(ws + OFF_POS);
    int*   w_amax  = (int*)(ws + OFF_AMAX);
    int*   w_pai   = (int*)(ws + OFF_PAI);
    int*   w_flags = (int*)(ws + OFF_FLAGS);

    hipMemsetAsync(w_pos, 0xFF, (size_t)N*4, stream);   // -1
    hipMemsetAsync(w_flags, 0, 8, stream);

    k_diff<<<1, 64, 0, stream>>>(posses, w_diff);
    k_prep_m<<<M/256, 256, 0, stream>>>(ssf, scoords, gt, ran, w_diff,
                                        w_al, w_rnssf, w_updf, w_gtc);
    k_prep_n<<<N/256, 256, 0, stream>>>(mf, w_rnmf, w_nmf2);
    k_argmin<<<dim3(M/256, NSPA), 256, 0, stream>>>(mf, ori, w_rnmf, ssf,
                                                    w_al, w_rnssf, w_pav, w_pai);
    k_argmin_reduce<<<M/256, 256, 0, stream>>>(w_pav, w_pai, w_smi, out_smi);
    k_uw_part<<<dim3(N/256, NSPB), 256, 0, stream>>>(mf, ori, w_nmf2, w_smi,
                                                     w_gtc, w_updf, w_pb);
    k_uw_final<<<N/256, 256, 0, stream>>>(w_pb, svp, out_uw, out_spu);
    k_scatter_pre<<<LG/256, 256, 0, stream>>>(w_smi, w_gtc, out_spu, w_vals, w_pos, w_flags);
    k_scatter_apply<<<LG/256, 256, 0, stream>>>(w_smi, w_gtc, w_vals, w_pos, w_flags, out_spu);
    k_trust_pre<<<N/256, 256, 0, stream>>>(out_spu, w_maxv, w_amax, w_flags);
    k_finalize<<<N/256, 256, 0, stream>>>(mf, ori, w_maxv, w_amax, w_flags,
                                          out_trust, out_mf, out_ori, out_pre);
}

// Round 2
// 769.810 us; speedup vs baseline: 1.3535x; 1.3535x over previous
//
#include <hip/hip_runtime.h>
#include <math.h>

#define N 8192
#define M 8192
#define C 96
#define OUT 20
#define LG 2048

#define NSPA 8    // n-splits for argmin pass (pass A)
#define NSPB 8    // m-splits for uw pass (pass B)
#define KC 32     // c-chunk staged per sB load

// ---------------- workspace layout (bytes) ----------------
constexpr size_t OFF_DIFF  = 0;
constexpr size_t OFF_AL    = 256;
constexpr size_t OFF_ANORM = OFF_AL    + (size_t)M*3*4;
constexpr size_t OFF_BNORM = OFF_ANORM + (size_t)M*C*4;
constexpr size_t OFF_NMF2  = OFF_BNORM + (size_t)N*C*4;
constexpr size_t OFF_UPDF  = OFF_NMF2  + (size_t)N*4;
constexpr size_t OFF_GTC   = OFF_UPDF  + (size_t)M*4;
constexpr size_t OFF_SMI   = OFF_GTC   + (size_t)M*4;
constexpr size_t OFF_MIDF  = OFF_SMI   + (size_t)M*4;
constexpr size_t OFF_MIDN2 = OFF_MIDF  + (size_t)M*C*4;
constexpr size_t OFF_MIDC  = OFF_MIDN2 + (size_t)M*4;
constexpr size_t OFF_PAV   = OFF_MIDC  + (size_t)M*3*4;
constexpr size_t OFF_PAI   = OFF_PAV   + (size_t)M*NSPA*4;
constexpr size_t OFF_PB    = OFF_PAI   + (size_t)M*NSPA*4;
constexpr size_t OFF_VALS  = OFF_PB    + (size_t)NSPB*N*OUT*4;
constexpr size_t OFF_POS   = OFF_VALS  + (size_t)LG*4;
constexpr size_t OFF_MAXV  = OFF_POS   + (size_t)N*4;
constexpr size_t OFF_AMAX  = OFF_MAXV  + (size_t)N*4;
constexpr size_t OFF_FLAGS = OFF_AMAX  + (size_t)N*4;

// ---------------------------------------------------------------- 4x4 inverse
__global__ void k_diff(const float* __restrict__ posses, float* __restrict__ diff) {
    if (threadIdx.x != 0 || blockIdx.x != 0) return;
    float a[4][8];
    for (int i = 0; i < 4; i++)
        for (int j = 0; j < 4; j++) {
            a[i][j]     = posses[16 + i*4 + j];   // posses[1]
            a[i][4 + j] = (i == j) ? 1.f : 0.f;
        }
    for (int col = 0; col < 4; col++) {
        int piv = col; float mx = fabsf(a[col][col]);
        for (int r = col + 1; r < 4; r++) {
            float v = fabsf(a[r][col]);
            if (v > mx) { mx = v; piv = r; }
        }
        if (piv != col)
            for (int j = 0; j < 8; j++) { float t = a[col][j]; a[col][j] = a[piv][j]; a[piv][j] = t; }
        float inv = 1.0f / a[col][col];
        for (int j = 0; j < 8; j++) a[col][j] *= inv;
        for (int r = 0; r < 4; r++) {
            if (r == col) continue;
            float f = a[r][col];
            for (int j = 0; j < 8; j++) a[r][j] -= f * a[col][j];
        }
    }
    for (int i = 0; i < 4; i++)
        for (int j = 0; j < 4; j++) {
            float s = 0.f;
            for (int k = 0; k < 4; k++) s += a[i][4 + k] * posses[k*4 + j];
            diff[i*4 + j] = s;
        }
}

// ---------------------------------------------------------------- per-m prep
__global__ void k_prep_m(const float* __restrict__ ssf, const float* __restrict__ scoords,
                         const float* __restrict__ gt, const int* __restrict__ ran_mask,
                         const float* __restrict__ diff,
                         float* __restrict__ al, float* __restrict__ anorm,
                         float* __restrict__ updf, int* __restrict__ gtcls) {
    int m = blockIdx.x * 256 + threadIdx.x;
    if (m >= M) return;
    float x = scoords[m*3], y = scoords[m*3+1], z = scoords[m*3+2];
    #pragma unroll
    for (int j = 0; j < 3; j++)
        al[m*3 + j] = diff[j*4+0]*x + diff[j*4+1]*y + diff[j*4+2]*z + diff[j*4+3];
    float s = 0.f;
    const float4* r4 = (const float4*)(ssf + (size_t)m * C);
    float4 row[24];
    #pragma unroll
    for (int c = 0; c < 24; c++) {
        float4 v = r4[c];
        row[c] = v;
        s += v.x*v.x + v.y*v.y + v.z*v.z + v.w*v.w;
    }
    float rn = 1.0f / sqrtf(s);
    float4* w4 = (float4*)(anorm + (size_t)m * C);
    #pragma unroll
    for (int c = 0; c < 24; c++) {
        float4 v = row[c];
        v.x *= rn; v.y *= rn; v.z *= rn; v.w *= rn;
        w4[c] = v;
    }
    int best = 0; float bv = gt[(size_t)m*OUT];
    #pragma unroll
    for (int k = 1; k < OUT; k++) {
        float v = gt[(size_t)m*OUT + k];
        if (v > bv) { bv = v; best = k; }
    }
    gtcls[m] = best;
    updf[m] = (best < 9 || m < LG || ran_mask[m] == 1) ? 1.f : 0.f;
}

// ---------------------------------------------------------------- per-n prep
__global__ void k_prep_n(const float* __restrict__ mf, float* __restrict__ bnorm,
                         float* __restrict__ nmf2) {
    int n = blockIdx.x * 256 + threadIdx.x;
    if (n >= N) return;
    float s = 0.f;
    const float4* r4 = (const float4*)(mf + (size_t)n * C);
    float4 row[24];
    #pragma unroll
    for (int c = 0; c < 24; c++) {
        float4 v = r4[c];
        row[c] = v;
        s += v.x*v.x + v.y*v.y + v.z*v.z + v.w*v.w;
    }
    nmf2[n] = s;
    float rn = 1.0f / sqrtf(s);
    float4* w4 = (float4*)(bnorm + (size_t)n * C);
    #pragma unroll
    for (int c = 0; c < 24; c++) {
        float4 v = row[c];
        v.x *= rn; v.y *= rn; v.z *= rn; v.w *= rn;
        w4[c] = v;
    }
}

// ---------------------------------------------------------------- pass A: argmin over n per m
// 128m x 128n block tile, 8x8 per thread, sA resident (96x128), sB chunked (KCx128)
__global__ __launch_bounds__(256, 2) void k_argmin(
        const float* __restrict__ anorm, const float* __restrict__ bnorm,
        const float* __restrict__ al, const float* __restrict__ ori,
        float* __restrict__ pav, int* __restrict__ pai) {
    __shared__ float sA[96*128];
    __shared__ float sB[KC*128];
    const int t = threadIdx.x;
    const int tx = t & 15, ty = t >> 4;
    const int m0 = blockIdx.x * 128;
    const int sp = blockIdx.y;

    {   // stage sA c-major: 2 threads/row, 12 float4 each
        const int r = t >> 1, h = t & 1;
        const float4* src = (const float4*)(anorm + (size_t)(m0 + r) * C) + h*12;
        #pragma unroll
        for (int q = 0; q < 12; q++) {
            float4 v = src[q];
            int c = h*48 + q*4;
            sA[(c+0)*128 + r] = v.x;
            sA[(c+1)*128 + r] = v.y;
            sA[(c+2)*128 + r] = v.z;
            sA[(c+3)*128 + r] = v.w;
        }
    }
    float mcx[8], mcy[8], mcz[8];
    #pragma unroll
    for (int i = 0; i < 8; i++) {
        int mm = m0 + ty*4 + (i&3) + (i>>2)*64;
        mcx[i] = al[mm*3+0]; mcy[i] = al[mm*3+1]; mcz[i] = al[mm*3+2];
    }
    float best[8]; int bidx[8];
    #pragma unroll
    for (int i = 0; i < 8; i++) { best[i] = 3.4e38f; bidx[i] = 0; }

    const int nbeg = sp * (N / NSPA);
    for (int n0 = nbeg; n0 < nbeg + N / NSPA; n0 += 128) {
        float acc[8][8];
        #pragma unroll
        for (int i = 0; i < 8; i++)
            #pragma unroll
            for (int j = 0; j < 8; j++) acc[i][j] = 0.f;

        for (int cc = 0; cc < C; cc += KC) {
            __syncthreads();
            {   // stage sB chunk c-major: 2 threads/row, 4 float4 each
                const int r = t >> 1, h = t & 1;
                const float4* src = (const float4*)(bnorm + (size_t)(n0 + r) * C + cc) + h*4;
                #pragma unroll
                for (int q = 0; q < 4; q++) {
                    float4 v = src[q];
                    int c = h*16 + q*4;
                    sB[(c+0)*128 + r] = v.x;
                    sB[(c+1)*128 + r] = v.y;
                    sB[(c+2)*128 + r] = v.z;
                    sB[(c+3)*128 + r] = v.w;
                }
            }
            __syncthreads();
            const float* sAc = sA + cc*128;
            #pragma unroll 4
            for (int c = 0; c < KC; c++) {
                float4 a0 = *(const float4*)&sAc[c*128 + ty*4];
                float4 a1 = *(const float4*)&sAc[c*128 + 64 + ty*4];
                float4 b0 = *(const float4*)&sB[c*128 + tx*4];
                float4 b1 = *(const float4*)&sB[c*128 + 64 + tx*4];
                float av[8] = {a0.x,a0.y,a0.z,a0.w,a1.x,a1.y,a1.z,a1.w};
                float bv[8] = {b0.x,b0.y,b0.z,b0.w,b1.x,b1.y,b1.z,b1.w};
                #pragma unroll
                for (int i = 0; i < 8; i++)
                    #pragma unroll
                    for (int j = 0; j < 8; j++)
                        acc[i][j] = fmaf(av[i], bv[j], acc[i][j]);
            }
        }
        // epilogue: sim + running argmin
        #pragma unroll
        for (int j = 0; j < 8; j++) {
            int nn = n0 + tx*4 + (j&3) + (j>>2)*64;
            float ncx = ori[nn*3+0], ncy = ori[nn*3+1], ncz = ori[nn*3+2];
            #pragma unroll
            for (int i = 0; i < 8; i++) {
                float dx = mcx[i]-ncx, dy = mcy[i]-ncy, dz = mcz[i]-ncz;
                float d2 = dx*dx + dy*dy + dz*dz;
                float sim = 2.0f - acc[i][j] - __expf(-2.0f*d2);
                if (sim < best[i]) { best[i] = sim; bidx[i] = nn; }
            }
        }
    }
    // reduce over the 16 tx lanes (lane bits 0-3), tie-break smaller n
    #pragma unroll
    for (int i = 0; i < 8; i++) {
        float bv = best[i]; int bi = bidx[i];
        #pragma unroll
        for (int d = 1; d < 16; d <<= 1) {
            float ov = __shfl_xor(bv, d, 64);
            int   oi = __shfl_xor(bi, d, 64);
            if (ov < bv || (ov == bv && oi < bi)) { bv = ov; bi = oi; }
        }
        if (tx == 0) {
            int mm = m0 + ty*4 + (i&3) + (i>>2)*64;
            pav[(size_t)sp*M + mm] = bv;
            pai[(size_t)sp*M + mm] = bi;
        }
    }
}

__global__ void k_argmin_reduce(const float* __restrict__ pav, const int* __restrict__ pai,
                                int* __restrict__ smi, float* __restrict__ out_smi) {
    int m = blockIdx.x * 256 + threadIdx.x;
    if (m >= M) return;
    float best = 3.4e38f; int bidx = 0;
    for (int sp = 0; sp < NSPA; sp++) {
        float v = pav[(size_t)sp * M + m];
        int   i = pai[(size_t)sp * M + m];
        if (v < best || (v == best && i < bidx)) { best = v; bidx = i; }
    }
    smi[m] = bidx;
    out_smi[m] = (float)bidx;
}

// ---------------------------------------------------------------- gather mid rows contiguous
__global__ void k_gather_mid(const int* __restrict__ smi, const float* __restrict__ mf,
                             const float* __restrict__ nmf2, const float* __restrict__ ori,
                             float* __restrict__ midf, float* __restrict__ midn2,
                             float* __restrict__ midc) {
    int t = threadIdx.x;
    int r = blockIdx.x * 128 + (t >> 1);
    int h = t & 1;
    int s = smi[r];
    const float4* src = (const float4*)(mf + (size_t)s * C) + h*12;
    float4* dst = (float4*)(midf + (size_t)r * C) + h*12;
    #pragma unroll
    for (int q = 0; q < 12; q++) dst[q] = src[q];
    if (h == 0) {
        midn2[r] = nmf2[s];
        midc[r*3+0] = ori[s*3+0];
        midc[r*3+1] = ori[s*3+1];
        midc[r*3+2] = ori[s*3+2];
    }
}

// ---------------------------------------------------------------- pass B: class-binned weight sums
// 128n x 128m block tile, 8x8 per thread; bins[128][21] in LDS via ds atomics
__global__ __launch_bounds__(256, 2) void k_uw(
        const float* __restrict__ mf, const float* __restrict__ nmf2,
        const float* __restrict__ ori,
        const float* __restrict__ midf, const float* __restrict__ midn2,
        const float* __restrict__ midc, const int* __restrict__ gtcls,
        const float* __restrict__ updf, float* __restrict__ pb) {
    __shared__ float sA[96*128];
    __shared__ float sB[KC*128];
    __shared__ float bins[128*21];
    const int t = threadIdx.x;
    const int tx = t & 15, ty = t >> 4;
    const int n0 = blockIdx.x * 128;
    const int sp = blockIdx.y;

    {   // stage sA (raw mf rows) c-major
        const int r = t >> 1, h = t & 1;
        const float4* src = (const float4*)(mf + (size_t)(n0 + r) * C) + h*12;
        #pragma unroll
        for (int q = 0; q < 12; q++) {
            float4 v = src[q];
            int c = h*48 + q*4;
            sA[(c+0)*128 + r] = v.x;
            sA[(c+1)*128 + r] = v.y;
            sA[(c+2)*128 + r] = v.z;
            sA[(c+3)*128 + r] = v.w;
        }
    }
    for (int i = t; i < 128*21; i += 256) bins[i] = 0.f;

    float nn2[8], ncx[8], ncy[8], ncz[8];
    #pragma unroll
    for (int i = 0; i < 8; i++) {
        int nn = n0 + ty*4 + (i&3) + (i>>2)*64;
        nn2[i] = nmf2[nn];
        ncx[i] = ori[nn*3+0]; ncy[i] = ori[nn*3+1]; ncz[i] = ori[nn*3+2];
    }

    const int mbeg = sp * (M / NSPB);
    for (int m0 = mbeg; m0 < mbeg + M / NSPB; m0 += 128) {
        float acc[8][8];
        #pragma unroll
        for (int i = 0; i < 8; i++)
            #pragma unroll
            for (int j = 0; j < 8; j++) acc[i][j] = 0.f;

        for (int cc = 0; cc < C; cc += KC) {
            __syncthreads();
            {
                const int r = t >> 1, h = t & 1;
                const float4* src = (const float4*)(midf + (size_t)(m0 + r) * C + cc) + h*4;
                #pragma unroll
                for (int q = 0; q < 4; q++) {
                    float4 v = src[q];
                    int c = h*16 + q*4;
                    sB[(c+0)*128 + r] = v.x;
                    sB[(c+1)*128 + r] = v.y;
                    sB[(c+2)*128 + r] = v.z;
                    sB[(c+3)*128 + r] = v.w;
                }
            }
            __syncthreads();
            const float* sAc = sA + cc*128;
            #pragma unroll 4
            for (int c = 0; c < KC; c++) {
                float4 a0 = *(const float4*)&sAc[c*128 + ty*4];
                float4 a1 = *(const float4*)&sAc[c*128 + 64 + ty*4];
                float4 b0 = *(const float4*)&sB[c*128 + tx*4];
                float4 b1 = *(const float4*)&sB[c*128 + 64 + tx*4];
                float av[8] = {a0.x,a0.y,a0.z,a0.w,a1.x,a1.y,a1.z,a1.w};
                float bv[8] = {b0.x,b0.y,b0.z,b0.w,b1.x,b1.y,b1.z,b1.w};
                #pragma unroll
                for (int i = 0; i < 8; i++)
                    #pragma unroll
                    for (int j = 0; j < 8; j++)
                        acc[i][j] = fmaf(av[i], bv[j], acc[i][j]);
            }
        }
        // epilogue: w, fold into per-n class bins
        #pragma unroll
        for (int j = 0; j < 8; j++) {
            int mm = m0 + tx*4 + (j&3) + (j>>2)*64;
            float mn2 = midn2[mm];
            float mcx = midc[mm*3+0], mcy = midc[mm*3+1], mcz = midc[mm*3+2];
            float mu  = updf[mm];
            int   mcl = gtcls[mm];
            #pragma unroll
            for (int i = 0; i < 8; i++) {
                float fd = fmaxf(nn2[i] + mn2 - 2.0f*acc[i][j], 0.0f);
                float dx = ncx[i]-mcx, dy = ncy[i]-mcy, dz = ncz[i]-mcz;
                float dc = dx*dx + dy*dy + dz*dz;
                float w = __expf(-8.0f*dc - (0.5f/0.09f)*fd) * mu;
                int nl = ty*4 + (i&3) + (i>>2)*64;
                atomicAdd(&bins[nl*21 + mcl], w);
            }
        }
    }
    __syncthreads();
    size_t base = ((size_t)sp*N + n0) * OUT;
    for (int i = t; i < 128*OUT; i += 256)
        pb[base + i] = bins[(i/OUT)*21 + (i%OUT)];
}

__global__ void k_uw_final(const float* __restrict__ pb, const float* __restrict__ svp,
                           float* __restrict__ out_uw, float* __restrict__ out_spu) {
    int n = blockIdx.x * 256 + threadIdx.x;
    if (n >= N) return;
    float s[OUT];
    #pragma unroll
    for (int k = 0; k < OUT; k++) s[k] = 0.f;
    for (int sp = 0; sp < NSPB; sp++) {
        size_t base = ((size_t)sp * N + n) * OUT;
        #pragma unroll
        for (int k = 0; k < OUT; k++) s[k] += pb[base + k];
    }
    float tot = 0.f;
    #pragma unroll
    for (int k = 0; k < OUT; k++) tot += s[k];
    float rden = 1.0f / (tot + 1e-16f);
    float p[OUT]; float mx = -3.4e38f;
    #pragma unroll
    for (int k = 0; k < OUT; k++) { p[k] = svp[(size_t)n*OUT + k]; mx = fmaxf(mx, p[k]); }
    float es = 0.f;
    #pragma unroll
    for (int k = 0; k < OUT; k++) { p[k] = __expf(p[k] - mx); es += p[k]; }
    float res = 1.0f / es;
    #pragma unroll
    for (int k = 0; k < OUT; k++) {
        float uw = s[k] * rden;
        out_uw[(size_t)n*OUT + k] = uw;
        out_spu[(size_t)n*OUT + k] = 0.5f * (p[k] * res) + 0.5f * uw;
    }
}

// ---------------------------------------------------------------- scatter (lg rows, last-wins)
__global__ void k_scatter_pre(const int* __restrict__ smi, const int* __restrict__ gtcls,
                              const float* __restrict__ spu, float* __restrict__ vals,
                              int* __restrict__ pos, int* __restrict__ flags) {
    int i = blockIdx.x * 256 + threadIdx.x;
    if (i >= LG) return;
    int idx = smi[i];
    float v = spu[(size_t)idx*OUT + gtcls[i]];
    vals[i] = v;
    if (v > 0.1f) atomicOr(&flags[0], 1);
    atomicMax(&pos[idx], i);
}

__global__ void k_scatter_apply(const int* __restrict__ smi, const int* __restrict__ gtcls,
                                const float* __restrict__ vals, const int* __restrict__ pos,
                                const int* __restrict__ flags, float* __restrict__ spu) {
    int i = blockIdx.x * 256 + threadIdx.x;
    if (i >= LG) return;
    int idx = smi[i];
    if (pos[idx] != i) return;               // last occurrence wins (np semantics)
    float v = vals[i];
    bool tmp = flags[0] ? (v > 0.1f) : (v > 0.0f);
    if (!tmp) return;                        // else-branch writes row unchanged: no-op
    int cls = gtcls[i];
    #pragma unroll
    for (int k = 0; k < OUT; k++) spu[(size_t)idx*OUT + k] = (k == cls) ? 1.0f : 0.0f;
}

// ---------------------------------------------------------------- trust / finalize
__global__ void k_trust_pre(const float* __restrict__ spu, float* __restrict__ maxv,
                            int* __restrict__ amax, int* __restrict__ flags) {
    int n = blockIdx.x * 256 + threadIdx.x;
    if (n >= N) return;
    float best = spu[(size_t)n*OUT]; int bi = 0;
    #pragma unroll
    for (int k = 1; k < OUT; k++) {
        float v = spu[(size_t)n*OUT + k];
        if (v > best) { best = v; bi = k; }   // strict >: first occurrence
    }
    maxv[n] = best; amax[n] = bi;
    if (best >= 0.9f) atomicOr(&flags[1], 1);
}

__global__ void k_finalize(const float* __restrict__ mf, const float* __restrict__ ori,
                           const float* __restrict__ maxv, const int* __restrict__ amax,
                           const int* __restrict__ flags,
                           float* __restrict__ out_trust, float* __restrict__ out_mf,
                           float* __restrict__ out_ori, float* __restrict__ out_pre) {
    int n = blockIdx.x * 256 + threadIdx.x;
    if (n >= N) return;
    float mv = maxv[n];
    bool tr = flags[1] ? (mv >= 0.9f) : (mv >= 0.85f);
    float m = tr ? 1.f : 0.f;
    out_trust[n] = m;
    const float4* src = (const float4*)(mf + (size_t)n * C);
    float4* dst = (float4*)(out_mf + (size_t)n * C);
    #pragma unroll
    for (int c = 0; c < 24; c++) {
        float4 v = src[c];
        v.x *= m; v.y *= m; v.z *= m; v.w *= m;
        dst[c] = v;
    }
    out_ori[n*3]   = ori[n*3]   * m;
    out_ori[n*3+1] = ori[n*3+1] * m;
    out_ori[n*3+2] = ori[n*3+2] * m;
    int bi = amax[n];
    #pragma unroll
    for (int k = 0; k < OUT; k++) out_pre[(size_t)n*OUT + k] = (k == bi) ? m : 0.f;
}

// ---------------------------------------------------------------- launch
extern "C" void kernel_launch(void* const* d_in, const int* in_sizes, int n_in,
                              void* d_out, int out_size, void* d_ws, size_t ws_size,
                              hipStream_t stream) {
    (void)in_sizes; (void)n_in; (void)out_size; (void)ws_size;
    const float* ssf     = (const float*)d_in[0];
    const float* scoords = (const float*)d_in[1];
    const float* gt      = (const float*)d_in[2];
    const float* svp     = (const float*)d_in[3];
    const float* mf      = (const float*)d_in[4];
    const float* ori     = (const float*)d_in[5];
    const float* posses  = (const float*)d_in[6];
    const int*   ran     = (const int*)d_in[7];

    float* out = (float*)d_out;
    float* out_trust = out;
    float* out_mf    = out_trust + N;
    float* out_ori   = out_mf + (size_t)N*C;
    float* out_pre   = out_ori + (size_t)N*3;
    float* out_uw    = out_pre + (size_t)N*OUT;
    float* out_spu   = out_uw  + (size_t)N*OUT;
    float* out_smi   = out_spu + (size_t)N*OUT;

    char* ws = (char*)d_ws;
    float* w_diff  = (float*)(ws + OFF_DIFF);
    float* w_al    = (float*)(ws + OFF_AL);
    float* w_anorm = (float*)(ws + OFF_ANORM);
    float* w_bnorm = (float*)(ws + OFF_BNORM);
    float* w_nmf2  = (float*)(ws + OFF_NMF2);
    float* w_updf  = (float*)(ws + OFF_UPDF);
    int*   w_gtc   = (int*)(ws + OFF_GTC);
    int*   w_smi   = (int*)(ws + OFF_SMI);
    float* w_midf  = (float*)(ws + OFF_MIDF);
    float* w_midn2 = (float*)(ws + OFF_MIDN2);
    float* w_midc  = (float*)(ws + OFF_MIDC);
    float* w_pav   = (float*)(ws + OFF_PAV);
    int*   w_pai   = (int*)(ws + OFF_PAI);
    float* w_pb    = (float*)(ws + OFF_PB);
    float* w_vals  = (float*)(ws + OFF_VALS);
    int*   w_pos   = (int*)(ws + OFF_POS);
    float* w_maxv  = (float*)(ws + OFF_MAXV);
    int*   w_amax  = (int*)(ws + OFF_AMAX);
    int*   w_flags = (int*)(ws + OFF_FLAGS);

    hipMemsetAsync(w_pos, 0xFF, (size_t)N*4, stream);   // -1
    hipMemsetAsync(w_flags, 0, 8, stream);

    k_diff<<<1, 64, 0, stream>>>(posses, w_diff);
    k_prep_m<<<M/256, 256, 0, stream>>>(ssf, scoords, gt, ran, w_diff,
                                        w_al, w_anorm, w_updf, w_gtc);
    k_prep_n<<<N/256, 256, 0, stream>>>(mf, w_bnorm, w_nmf2);
    k_argmin<<<dim3(M/128, NSPA), 256, 0, stream>>>(w_anorm, w_bnorm, w_al, ori,
                                                    w_pav, w_pai);
    k_argmin_reduce<<<M/256, 256, 0, stream>>>(w_pav, w_pai, w_smi, out_smi);
    k_gather_mid<<<M/128, 256, 0, stream>>>(w_smi, mf, w_nmf2, ori,
                                            w_midf, w_midn2, w_midc);
    k_uw<<<dim3(N/128, NSPB), 256, 0, stream>>>(mf, w_nmf2, ori, w_midf, w_midn2,
                                                w_midc, w_gtc, w_updf, w_pb);
    k_uw_final<<<N/256, 256, 0, stream>>>(w_pb, svp, out_uw, out_spu);
    k_scatter_pre<<<LG/256, 256, 0, stream>>>(w_smi, w_gtc, out_spu, w_vals, w_pos, w_flags);
    k_scatter_apply<<<LG/256, 256, 0, stream>>>(w_smi, w_gtc, w_vals, w_pos, w_flags, out_spu);
    k_trust_pre<<<N/256, 256, 0, stream>>>(out_spu, w_maxv, w_amax, w_flags);
    k_finalize<<<N/256, 256, 0, stream>>>(mf, ori, w_maxv, w_amax, w_flags,
                                          out_trust, out_mf, out_ori, out_pre);
}

// Round 3
// 580.472 us; speedup vs baseline: 1.7950x; 1.3262x over previous
//
#include <hip/hip_runtime.h>
#include <math.h>

#define N 8192
#define M 8192
#define C 96
#define OUT 20
#define LG 2048

#define NSPA 8    // n-splits for argmin pass (pass A)
#define NSPB 8    // m-tile stride for uw pass (pass B)
#define KC 32     // c-chunk staged per sB load

// ---------------- workspace layout (bytes) ----------------
constexpr size_t OFF_DIFF  = 0;
constexpr size_t OFF_AL    = 256;
constexpr size_t OFF_ANORM = OFF_AL    + (size_t)M*3*4;
constexpr size_t OFF_BNORM = OFF_ANORM + (size_t)M*C*4;
constexpr size_t OFF_NMF2  = OFF_BNORM + (size_t)N*C*4;
constexpr size_t OFF_UPDF  = OFF_NMF2  + (size_t)N*4;
constexpr size_t OFF_GTC   = OFF_UPDF  + (size_t)M*4;
constexpr size_t OFF_SMI   = OFF_GTC   + (size_t)M*4;
constexpr size_t OFF_PERM  = OFF_SMI   + (size_t)M*4;
constexpr size_t OFF_MIDF  = OFF_PERM  + (size_t)M*4;
constexpr size_t OFF_MIDN2 = OFF_MIDF  + (size_t)(M+128)*C*4;
constexpr size_t OFF_MIDC  = OFF_MIDN2 + (size_t)(M+128)*4;
constexpr size_t OFF_CLS   = OFF_MIDC  + (size_t)(M+128)*3*4;
constexpr size_t OFF_PAV   = OFF_CLS   + (size_t)(M+128)*4;
constexpr size_t OFF_PAI   = OFF_PAV   + (size_t)M*NSPA*4;
constexpr size_t OFF_PB    = OFF_PAI   + (size_t)M*NSPA*4;
constexpr size_t OFF_VALS  = OFF_PB    + (size_t)NSPB*N*OUT*4;
constexpr size_t OFF_POS   = OFF_VALS  + (size_t)LG*4;
constexpr size_t OFF_MAXV  = OFF_POS   + (size_t)N*4;
constexpr size_t OFF_AMAX  = OFF_MAXV  + (size_t)N*4;
constexpr size_t OFF_FLAGS = OFF_AMAX  + (size_t)N*4;
constexpr size_t OFF_CNT   = OFF_FLAGS + 64;               // 20 ints
constexpr size_t OFF_META  = OFF_CNT   + 128;              // [0]=Mact [1]=ntiles [2..21]=cursor

// ---------------------------------------------------------------- 4x4 inverse
__global__ void k_diff(const float* __restrict__ posses, float* __restrict__ diff) {
    if (threadIdx.x != 0 || blockIdx.x != 0) return;
    float a[4][8];
    for (int i = 0; i < 4; i++)
        for (int j = 0; j < 4; j++) {
            a[i][j]     = posses[16 + i*4 + j];   // posses[1]
            a[i][4 + j] = (i == j) ? 1.f : 0.f;
        }
    for (int col = 0; col < 4; col++) {
        int piv = col; float mx = fabsf(a[col][col]);
        for (int r = col + 1; r < 4; r++) {
            float v = fabsf(a[r][col]);
            if (v > mx) { mx = v; piv = r; }
        }
        if (piv != col)
            for (int j = 0; j < 8; j++) { float t = a[col][j]; a[col][j] = a[piv][j]; a[piv][j] = t; }
        float inv = 1.0f / a[col][col];
        for (int j = 0; j < 8; j++) a[col][j] *= inv;
        for (int r = 0; r < 4; r++) {
            if (r == col) continue;
            float f = a[r][col];
            for (int j = 0; j < 8; j++) a[r][j] -= f * a[col][j];
        }
    }
    for (int i = 0; i < 4; i++)
        for (int j = 0; j < 4; j++) {
            float s = 0.f;
            for (int k = 0; k < 4; k++) s += a[i][4 + k] * posses[k*4 + j];
            diff[i*4 + j] = s;
        }
}

// ---------------------------------------------------------------- per-m prep
__global__ void k_prep_m(const float* __restrict__ ssf, const float* __restrict__ scoords,
                         const float* __restrict__ gt, const int* __restrict__ ran_mask,
                         const float* __restrict__ diff,
                         float* __restrict__ al, float* __restrict__ anorm,
                         float* __restrict__ updf, int* __restrict__ gtcls) {
    int m = blockIdx.x * 256 + threadIdx.x;
    if (m >= M) return;
    float x = scoords[m*3], y = scoords[m*3+1], z = scoords[m*3+2];
    #pragma unroll
    for (int j = 0; j < 3; j++)
        al[m*3 + j] = diff[j*4+0]*x + diff[j*4+1]*y + diff[j*4+2]*z + diff[j*4+3];
    float s = 0.f;
    const float4* r4 = (const float4*)(ssf + (size_t)m * C);
    float4 row[24];
    #pragma unroll
    for (int c = 0; c < 24; c++) {
        float4 v = r4[c];
        row[c] = v;
        s += v.x*v.x + v.y*v.y + v.z*v.z + v.w*v.w;
    }
    float rn = 1.0f / sqrtf(s);
    float4* w4 = (float4*)(anorm + (size_t)m * C);
    #pragma unroll
    for (int c = 0; c < 24; c++) {
        float4 v = row[c];
        v.x *= rn; v.y *= rn; v.z *= rn; v.w *= rn;
        w4[c] = v;
    }
    int best = 0; float bv = gt[(size_t)m*OUT];
    #pragma unroll
    for (int k = 1; k < OUT; k++) {
        float v = gt[(size_t)m*OUT + k];
        if (v > bv) { bv = v; best = k; }
    }
    gtcls[m] = best;
    updf[m] = (best < 9 || m < LG || ran_mask[m] == 1) ? 1.f : 0.f;
}

// ---------------------------------------------------------------- per-n prep
__global__ void k_prep_n(const float* __restrict__ mf, float* __restrict__ bnorm,
                         float* __restrict__ nmf2) {
    int n = blockIdx.x * 256 + threadIdx.x;
    if (n >= N) return;
    float s = 0.f;
    const float4* r4 = (const float4*)(mf + (size_t)n * C);
    float4 row[24];
    #pragma unroll
    for (int c = 0; c < 24; c++) {
        float4 v = r4[c];
        row[c] = v;
        s += v.x*v.x + v.y*v.y + v.z*v.z + v.w*v.w;
    }
    nmf2[n] = s;
    float rn = 1.0f / sqrtf(s);
    float4* w4 = (float4*)(bnorm + (size_t)n * C);
    #pragma unroll
    for (int c = 0; c < 24; c++) {
        float4 v = row[c];
        v.x *= rn; v.y *= rn; v.z *= rn; v.w *= rn;
        w4[c] = v;
    }
}

// ---------------------------------------------------------------- pass A: argmin over n per m
__global__ __launch_bounds__(256, 2) void k_argmin(
        const float* __restrict__ anorm, const float* __restrict__ bnorm,
        const float* __restrict__ al, const float* __restrict__ ori,
        float* __restrict__ pav, int* __restrict__ pai) {
    __shared__ float sA[96*128];
    __shared__ float sB[KC*128];
    const int t = threadIdx.x;
    const int tx = t & 15, ty = t >> 4;
    const int m0 = blockIdx.x * 128;
    const int sp = blockIdx.y;

    {   // stage sA c-major: 2 threads/row, 12 float4 each
        const int r = t >> 1, h = t & 1;
        const float4* src = (const float4*)(anorm + (size_t)(m0 + r) * C) + h*12;
        #pragma unroll
        for (int q = 0; q < 12; q++) {
            float4 v = src[q];
            int c = h*48 + q*4;
            sA[(c+0)*128 + r] = v.x;
            sA[(c+1)*128 + r] = v.y;
            sA[(c+2)*128 + r] = v.z;
            sA[(c+3)*128 + r] = v.w;
        }
    }
    float mcx[8], mcy[8], mcz[8];
    #pragma unroll
    for (int i = 0; i < 8; i++) {
        int mm = m0 + ty*4 + (i&3) + (i>>2)*64;
        mcx[i] = al[mm*3+0]; mcy[i] = al[mm*3+1]; mcz[i] = al[mm*3+2];
    }
    float best[8]; int bidx[8];
    #pragma unroll
    for (int i = 0; i < 8; i++) { best[i] = 3.4e38f; bidx[i] = 0; }

    const int nbeg = sp * (N / NSPA);
    for (int n0 = nbeg; n0 < nbeg + N / NSPA; n0 += 128) {
        float acc[8][8];
        #pragma unroll
        for (int i = 0; i < 8; i++)
            #pragma unroll
            for (int j = 0; j < 8; j++) acc[i][j] = 0.f;

        for (int cc = 0; cc < C; cc += KC) {
            __syncthreads();
            {
                const int r = t >> 1, h = t & 1;
                const float4* src = (const float4*)(bnorm + (size_t)(n0 + r) * C + cc) + h*4;
                #pragma unroll
                for (int q = 0; q < 4; q++) {
                    float4 v = src[q];
                    int c = h*16 + q*4;
                    sB[(c+0)*128 + r] = v.x;
                    sB[(c+1)*128 + r] = v.y;
                    sB[(c+2)*128 + r] = v.z;
                    sB[(c+3)*128 + r] = v.w;
                }
            }
            __syncthreads();
            const float* sAc = sA + cc*128;
            #pragma unroll 4
            for (int c = 0; c < KC; c++) {
                float4 a0 = *(const float4*)&sAc[c*128 + ty*4];
                float4 a1 = *(const float4*)&sAc[c*128 + 64 + ty*4];
                float4 b0 = *(const float4*)&sB[c*128 + tx*4];
                float4 b1 = *(const float4*)&sB[c*128 + 64 + tx*4];
                float av[8] = {a0.x,a0.y,a0.z,a0.w,a1.x,a1.y,a1.z,a1.w};
                float bv[8] = {b0.x,b0.y,b0.z,b0.w,b1.x,b1.y,b1.z,b1.w};
                #pragma unroll
                for (int i = 0; i < 8; i++)
                    #pragma unroll
                    for (int j = 0; j < 8; j++)
                        acc[i][j] = fmaf(av[i], bv[j], acc[i][j]);
            }
        }
        #pragma unroll
        for (int j = 0; j < 8; j++) {
            int nn = n0 + tx*4 + (j&3) + (j>>2)*64;
            float ncx = ori[nn*3+0], ncy = ori[nn*3+1], ncz = ori[nn*3+2];
            #pragma unroll
            for (int i = 0; i < 8; i++) {
                float dx = mcx[i]-ncx, dy = mcy[i]-ncy, dz = mcz[i]-ncz;
                float d2 = dx*dx + dy*dy + dz*dz;
                float sim = 2.0f - acc[i][j] - __expf(-2.0f*d2);
                if (sim < best[i]) { best[i] = sim; bidx[i] = nn; }
            }
        }
    }
    #pragma unroll
    for (int i = 0; i < 8; i++) {
        float bv = best[i]; int bi = bidx[i];
        #pragma unroll
        for (int d = 1; d < 16; d <<= 1) {
            float ov = __shfl_xor(bv, d, 64);
            int   oi = __shfl_xor(bi, d, 64);
            if (ov < bv || (ov == bv && oi < bi)) { bv = ov; bi = oi; }
        }
        if (tx == 0) {
            int mm = m0 + ty*4 + (i&3) + (i>>2)*64;
            pav[(size_t)sp*M + mm] = bv;
            pai[(size_t)sp*M + mm] = bi;
        }
    }
}

__global__ void k_argmin_reduce(const float* __restrict__ pav, const int* __restrict__ pai,
                                int* __restrict__ smi, float* __restrict__ out_smi) {
    int m = blockIdx.x * 256 + threadIdx.x;
    if (m >= M) return;
    float best = 3.4e38f; int bidx = 0;
    for (int sp = 0; sp < NSPA; sp++) {
        float v = pav[(size_t)sp * M + m];
        int   i = pai[(size_t)sp * M + m];
        if (v < best || (v == best && i < bidx)) { best = v; bidx = i; }
    }
    smi[m] = bidx;
    out_smi[m] = (float)bidx;
}

// ---------------------------------------------------------------- counting sort by class (active only)
__global__ void k_hist(const int* __restrict__ gtcls, const float* __restrict__ updf,
                       int* __restrict__ cnt) {
    __shared__ int h[OUT];
    int t = threadIdx.x;
    if (t < OUT) h[t] = 0;
    __syncthreads();
    int m = blockIdx.x * 256 + t;
    if (m < M && updf[m] != 0.f) atomicAdd(&h[gtcls[m]], 1);
    __syncthreads();
    if (t < OUT) atomicAdd(&cnt[t], h[t]);
}

__global__ void k_scan(const int* __restrict__ cnt, int* __restrict__ meta) {
    if (threadIdx.x != 0 || blockIdx.x != 0) return;
    int run = 0;
    for (int k = 0; k < OUT; k++) { meta[2 + k] = run; run += cnt[k]; }
    meta[0] = run;                    // Mact
    meta[1] = (run + 127) / 128;      // ntiles
}

__global__ void k_permute(const int* __restrict__ gtcls, const float* __restrict__ updf,
                          int* __restrict__ meta, int* __restrict__ perm) {
    int m = blockIdx.x * 256 + threadIdx.x;
    if (m >= M) return;
    if (updf[m] == 0.f) return;
    int pos = atomicAdd(&meta[2 + gtcls[m]], 1);
    perm[pos] = m;
}

// gather sorted+compacted mid rows; pad tail tile with w=0 sentinels
__global__ void k_gather_sorted(const int* __restrict__ meta, const int* __restrict__ perm,
                                const int* __restrict__ smi, const int* __restrict__ gtcls,
                                const float* __restrict__ mf, const float* __restrict__ nmf2,
                                const float* __restrict__ ori,
                                float* __restrict__ midf, float* __restrict__ midn2,
                                float* __restrict__ midc, int* __restrict__ cls_s) {
    int r = blockIdx.x * 256 + threadIdx.x;
    int mact = meta[0];
    int mpad = ((mact + 127) / 128) * 128;
    if (r < mact) {
        int m = perm[r];
        int s = smi[m];
        const float4* src = (const float4*)(mf + (size_t)s * C);
        float4* dst = (float4*)(midf + (size_t)r * C);
        #pragma unroll
        for (int q = 0; q < 24; q++) dst[q] = src[q];
        midn2[r] = nmf2[s];
        midc[r*3+0] = ori[s*3+0];
        midc[r*3+1] = ori[s*3+1];
        midc[r*3+2] = ori[s*3+2];
        cls_s[r] = gtcls[m];
    } else if (r < mpad) {
        float4 z = {0.f,0.f,0.f,0.f};
        float4* dst = (float4*)(midf + (size_t)r * C);
        #pragma unroll
        for (int q = 0; q < 24; q++) dst[q] = z;
        midn2[r] = 1e9f;      // forces w = exp(-5.55e9) = 0 exactly
        midc[r*3+0] = 0.f; midc[r*3+1] = 0.f; midc[r*3+2] = 0.f;
        cls_s[r] = 0;
    }
}

// ---------------------------------------------------------------- pass B: class-binned weight sums
// m sorted by class + compacted: uniform-class tiles use shfl-reduce, no atomics
__global__ __launch_bounds__(256, 2) void k_uw(
        const float* __restrict__ mf, const float* __restrict__ nmf2,
        const float* __restrict__ ori,
        const float* __restrict__ midf, const float* __restrict__ midn2,
        const float* __restrict__ midc, const int* __restrict__ cls_s,
        const int* __restrict__ meta, float* __restrict__ pb) {
    __shared__ float sA[96*128];
    __shared__ float sB[KC*128];
    __shared__ float bins[128*21];
    __shared__ int   s_cl[128];
    const int t = threadIdx.x;
    const int tx = t & 15, ty = t >> 4;
    const int n0 = blockIdx.x * 128;
    const int sp = blockIdx.y;
    const int ntiles = meta[1];

    {   // stage sA (raw mf rows) c-major
        const int r = t >> 1, h = t & 1;
        const float4* src = (const float4*)(mf + (size_t)(n0 + r) * C) + h*12;
        #pragma unroll
        for (int q = 0; q < 12; q++) {
            float4 v = src[q];
            int c = h*48 + q*4;
            sA[(c+0)*128 + r] = v.x;
            sA[(c+1)*128 + r] = v.y;
            sA[(c+2)*128 + r] = v.z;
            sA[(c+3)*128 + r] = v.w;
        }
    }
    for (int i = t; i < 128*21; i += 256) bins[i] = 0.f;

    float nn2[8], ncx[8], ncy[8], ncz[8];
    #pragma unroll
    for (int i = 0; i < 8; i++) {
        int nn = n0 + ty*4 + (i&3) + (i>>2)*64;
        nn2[i] = nmf2[nn];
        ncx[i] = ori[nn*3+0]; ncy[i] = ori[nn*3+1]; ncz[i] = ori[nn*3+2];
    }

    for (int tile = sp; tile < ntiles; tile += NSPB) {
        const int m0 = tile * 128;
        __syncthreads();               // protect s_cl/bins vs previous epilogue
        if (t < 128) s_cl[t] = cls_s[m0 + t];

        float acc[8][8];
        #pragma unroll
        for (int i = 0; i < 8; i++)
            #pragma unroll
            for (int j = 0; j < 8; j++) acc[i][j] = 0.f;

        for (int cc = 0; cc < C; cc += KC) {
            __syncthreads();
            {
                const int r = t >> 1, h = t & 1;
                const float4* src = (const float4*)(midf + (size_t)(m0 + r) * C + cc) + h*4;
                #pragma unroll
                for (int q = 0; q < 4; q++) {
                    float4 v = src[q];
                    int c = h*16 + q*4;
                    sB[(c+0)*128 + r] = v.x;
                    sB[(c+1)*128 + r] = v.y;
                    sB[(c+2)*128 + r] = v.z;
                    sB[(c+3)*128 + r] = v.w;
                }
            }
            __syncthreads();
            const float* sAc = sA + cc*128;
            #pragma unroll 4
            for (int c = 0; c < KC; c++) {
                float4 a0 = *(const float4*)&sAc[c*128 + ty*4];
                float4 a1 = *(const float4*)&sAc[c*128 + 64 + ty*4];
                float4 b0 = *(const float4*)&sB[c*128 + tx*4];
                float4 b1 = *(const float4*)&sB[c*128 + 64 + tx*4];
                float av[8] = {a0.x,a0.y,a0.z,a0.w,a1.x,a1.y,a1.z,a1.w};
                float bv[8] = {b0.x,b0.y,b0.z,b0.w,b1.x,b1.y,b1.z,b1.w};
                #pragma unroll
                for (int i = 0; i < 8; i++)
                    #pragma unroll
                    for (int j = 0; j < 8; j++)
                        acc[i][j] = fmaf(av[i], bv[j], acc[i][j]);
            }
        }
        // epilogue
        const int cls0 = s_cl[0];
        if (cls0 == s_cl[127]) {       // uniform tile (sorted -> endpoints suffice)
            float rsum[8];
            #pragma unroll
            for (int i = 0; i < 8; i++) rsum[i] = 0.f;
            #pragma unroll
            for (int j = 0; j < 8; j++) {
                int mm = m0 + tx*4 + (j&3) + (j>>2)*64;
                float mn2 = midn2[mm];
                float mcx = midc[mm*3+0], mcy = midc[mm*3+1], mcz = midc[mm*3+2];
                #pragma unroll
                for (int i = 0; i < 8; i++) {
                    float fd = fmaxf(nn2[i] + mn2 - 2.0f*acc[i][j], 0.0f);
                    float dx = ncx[i]-mcx, dy = ncy[i]-mcy, dz = ncz[i]-mcz;
                    float dc = dx*dx + dy*dy + dz*dz;
                    rsum[i] += __expf(-8.0f*dc - (0.5f/0.09f)*fd);
                }
            }
            #pragma unroll
            for (int i = 0; i < 8; i++) {
                float v = rsum[i];
                v += __shfl_xor(v, 1, 64);
                v += __shfl_xor(v, 2, 64);
                v += __shfl_xor(v, 4, 64);
                v += __shfl_xor(v, 8, 64);
                if (tx == 0) {
                    int nl = ty*4 + (i&3) + (i>>2)*64;
                    bins[nl*21 + cls0] += v;   // distinct addresses: plain RMW
                }
            }
        } else {                        // boundary tile (rare): atomic fallback
            #pragma unroll
            for (int j = 0; j < 8; j++) {
                int col = tx*4 + (j&3) + (j>>2)*64;
                int mm = m0 + col;
                float mn2 = midn2[mm];
                float mcx = midc[mm*3+0], mcy = midc[mm*3+1], mcz = midc[mm*3+2];
                int   mcl = s_cl[col];
                #pragma unroll
                for (int i = 0; i < 8; i++) {
                    float fd = fmaxf(nn2[i] + mn2 - 2.0f*acc[i][j], 0.0f);
                    float dx = ncx[i]-mcx, dy = ncy[i]-mcy, dz = ncz[i]-mcz;
                    float dc = dx*dx + dy*dy + dz*dz;
                    float w = __expf(-8.0f*dc - (0.5f/0.09f)*fd);
                    int nl = ty*4 + (i&3) + (i>>2)*64;
                    atomicAdd(&bins[nl*21 + mcl], w);
                }
            }
        }
    }
    __syncthreads();
    size_t base = ((size_t)sp*N + n0) * OUT;
    for (int i = t; i < 128*OUT; i += 256)
        pb[base + i] = bins[(i/OUT)*21 + (i%OUT)];
}

__global__ void k_uw_final(const float* __restrict__ pb, const float* __restrict__ svp,
                           float* __restrict__ out_uw, float* __restrict__ out_spu) {
    int n = blockIdx.x * 256 + threadIdx.x;
    if (n >= N) return;
    float s[OUT];
    #pragma unroll
    for (int k = 0; k < OUT; k++) s[k] = 0.f;
    for (int sp = 0; sp < NSPB; sp++) {
        size_t base = ((size_t)sp * N + n) * OUT;
        #pragma unroll
        for (int k = 0; k < OUT; k++) s[k] += pb[base + k];
    }
    float tot = 0.f;
    #pragma unroll
    for (int k = 0; k < OUT; k++) tot += s[k];
    float rden = 1.0f / (tot + 1e-16f);
    float p[OUT]; float mx = -3.4e38f;
    #pragma unroll
    for (int k = 0; k < OUT; k++) { p[k] = svp[(size_t)n*OUT + k]; mx = fmaxf(mx, p[k]); }
    float es = 0.f;
    #pragma unroll
    for (int k = 0; k < OUT; k++) { p[k] = __expf(p[k] - mx); es += p[k]; }
    float res = 1.0f / es;
    #pragma unroll
    for (int k = 0; k < OUT; k++) {
        float uw = s[k] * rden;
        out_uw[(size_t)n*OUT + k] = uw;
        out_spu[(size_t)n*OUT + k] = 0.5f * (p[k] * res) + 0.5f * uw;
    }
}

// ---------------------------------------------------------------- scatter (lg rows, last-wins)
__global__ void k_scatter_pre(const int* __restrict__ smi, const int* __restrict__ gtcls,
                              const float* __restrict__ spu, float* __restrict__ vals,
                              int* __restrict__ pos, int* __restrict__ flags) {
    int i = blockIdx.x * 256 + threadIdx.x;
    if (i >= LG) return;
    int idx = smi[i];
    float v = spu[(size_t)idx*OUT + gtcls[i]];
    vals[i] = v;
    if (v > 0.1f) atomicOr(&flags[0], 1);
    atomicMax(&pos[idx], i);
}

__global__ void k_scatter_apply(const int* __restrict__ smi, const int* __restrict__ gtcls,
                                const float* __restrict__ vals, const int* __restrict__ pos,
                                const int* __restrict__ flags, float* __restrict__ spu) {
    int i = blockIdx.x * 256 + threadIdx.x;
    if (i >= LG) return;
    int idx = smi[i];
    if (pos[idx] != i) return;               // last occurrence wins (np semantics)
    float v = vals[i];
    bool tmp = flags[0] ? (v > 0.1f) : (v > 0.0f);
    if (!tmp) return;
    int cls = gtcls[i];
    #pragma unroll
    for (int k = 0; k < OUT; k++) spu[(size_t)idx*OUT + k] = (k == cls) ? 1.0f : 0.0f;
}

// ---------------------------------------------------------------- trust / finalize
__global__ void k_trust_pre(const float* __restrict__ spu, float* __restrict__ maxv,
                            int* __restrict__ amax, int* __restrict__ flags) {
    int n = blockIdx.x * 256 + threadIdx.x;
    if (n >= N) return;
    float best = spu[(size_t)n*OUT]; int bi = 0;
    #pragma unroll
    for (int k = 1; k < OUT; k++) {
        float v = spu[(size_t)n*OUT + k];
        if (v > best) { best = v; bi = k; }
    }
    maxv[n] = best; amax[n] = bi;
    if (best >= 0.9f) atomicOr(&flags[1], 1);
}

__global__ void k_finalize(const float* __restrict__ mf, const float* __restrict__ ori,
                           const float* __restrict__ maxv, const int* __restrict__ amax,
                           const int* __restrict__ flags,
                           float* __restrict__ out_trust, float* __restrict__ out_mf,
                           float* __restrict__ out_ori, float* __restrict__ out_pre) {
    int n = blockIdx.x * 256 + threadIdx.x;
    if (n >= N) return;
    float mv = maxv[n];
    bool tr = flags[1] ? (mv >= 0.9f) : (mv >= 0.85f);
    float m = tr ? 1.f : 0.f;
    out_trust[n] = m;
    const float4* src = (const float4*)(mf + (size_t)n * C);
    float4* dst = (float4*)(out_mf + (size_t)n * C);
    #pragma unroll
    for (int c = 0; c < 24; c++) {
        float4 v = src[c];
        v.x *= m; v.y *= m; v.z *= m; v.w *= m;
        dst[c] = v;
    }
    out_ori[n*3]   = ori[n*3]   * m;
    out_ori[n*3+1] = ori[n*3+1] * m;
    out_ori[n*3+2] = ori[n*3+2] * m;
    int bi = amax[n];
    #pragma unroll
    for (int k = 0; k < OUT; k++) out_pre[(size_t)n*OUT + k] = (k == bi) ? m : 0.f;
}

// ---------------------------------------------------------------- launch
extern "C" void kernel_launch(void* const* d_in, const int* in_sizes, int n_in,
                              void* d_out, int out_size, void* d_ws, size_t ws_size,
                              hipStream_t stream) {
    (void)in_sizes; (void)n_in; (void)out_size; (void)ws_size;
    const float* ssf     = (const float*)d_in[0];
    const float* scoords = (const float*)d_in[1];
    const float* gt      = (const float*)d_in[2];
    const float* svp     = (const float*)d_in[3];
    const float* mf      = (const float*)d_in[4];
    const float* ori     = (const float*)d_in[5];
    const float* posses  = (const float*)d_in[6];
    const int*   ran     = (const int*)d_in[7];

    float* out = (float*)d_out;
    float* out_trust = out;
    float* out_mf    = out_trust + N;
    float* out_ori   = out_mf + (size_t)N*C;
    float* out_pre   = out_ori + (size_t)N*3;
    float* out_uw    = out_pre + (size_t)N*OUT;
    float* out_spu   = out_uw  + (size_t)N*OUT;
    float* out_smi   = out_spu + (size_t)N*OUT;

    char* ws = (char*)d_ws;
    float* w_diff  = (float*)(ws + OFF_DIFF);
    float* w_al    = (float*)(ws + OFF_AL);
    float* w_anorm = (float*)(ws + OFF_ANORM);
    float* w_bnorm = (float*)(ws + OFF_BNORM);
    float* w_nmf2  = (float*)(ws + OFF_NMF2);
    float* w_updf  = (float*)(ws + OFF_UPDF);
    int*   w_gtc   = (int*)(ws + OFF_GTC);
    int*   w_smi   = (int*)(ws + OFF_SMI);
    int*   w_perm  = (int*)(ws + OFF_PERM);
    float* w_midf  = (float*)(ws + OFF_MIDF);
    float* w_midn2 = (float*)(ws + OFF_MIDN2);
    float* w_midc  = (float*)(ws + OFF_MIDC);
    int*   w_cls   = (int*)(ws + OFF_CLS);
    float* w_pav   = (float*)(ws + OFF_PAV);
    int*   w_pai   = (int*)(ws + OFF_PAI);
    float* w_pb    = (float*)(ws + OFF_PB);
    float* w_vals  = (float*)(ws + OFF_VALS);
    int*   w_pos   = (int*)(ws + OFF_POS);
    float* w_maxv  = (float*)(ws + OFF_MAXV);
    int*   w_amax  = (int*)(ws + OFF_AMAX);
    int*   w_flags = (int*)(ws + OFF_FLAGS);
    int*   w_cnt   = (int*)(ws + OFF_CNT);
    int*   w_meta  = (int*)(ws + OFF_META);

    hipMemsetAsync(w_pos, 0xFF, (size_t)N*4, stream);   // -1
    hipMemsetAsync(w_flags, 0, 8, stream);
    hipMemsetAsync(w_cnt, 0, OUT*4, stream);

    k_diff<<<1, 64, 0, stream>>>(posses, w_diff);
    k_prep_m<<<M/256, 256, 0, stream>>>(ssf, scoords, gt, ran, w_diff,
                                        w_al, w_anorm, w_updf, w_gtc);
    k_prep_n<<<N/256, 256, 0, stream>>>(mf, w_bnorm, w_nmf2);
    k_argmin<<<dim3(M/128, NSPA), 256, 0, stream>>>(w_anorm, w_bnorm, w_al, ori,
                                                    w_pav, w_pai);
    k_argmin_reduce<<<M/256, 256, 0, stream>>>(w_pav, w_pai, w_smi, out_smi);
    k_hist<<<M/256, 256, 0, stream>>>(w_gtc, w_updf, w_cnt);
    k_scan<<<1, 64, 0, stream>>>(w_cnt, w_meta);
    k_permute<<<M/256, 256, 0, stream>>>(w_gtc, w_updf, w_meta, w_perm);
    k_gather_sorted<<<(M+128+255)/256, 256, 0, stream>>>(w_meta, w_perm, w_smi, w_gtc,
                                                         mf, w_nmf2, ori,
                                                         w_midf, w_midn2, w_midc, w_cls);
    k_uw<<<dim3(N/128, NSPB), 256, 0, stream>>>(mf, w_nmf2, ori, w_midf, w_midn2,
                                                w_midc, w_cls, w_meta, w_pb);
    k_uw_final<<<N/256, 256, 0, stream>>>(w_pb, svp, out_uw, out_spu);
    k_scatter_pre<<<LG/256, 256, 0, stream>>>(w_smi, w_gtc, out_spu, w_vals, w_pos, w_flags);
    k_scatter_apply<<<LG/256, 256, 0, stream>>>(w_smi, w_gtc, w_vals, w_pos, w_flags, out_spu);
    k_trust_pre<<<N/256, 256, 0, stream>>>(out_spu, w_maxv, w_amax, w_flags);
    k_finalize<<<N/256, 256, 0, stream>>>(mf, ori, w_maxv, w_amax, w_flags,
                                          out_trust, out_mf, out_ori, out_pre);
}